// Round 13
// baseline (2933.588 us; speedup 1.0000x reference)
//
#include <hip/hip_runtime.h>

// Autoregressive FFNN. out[b,0]=0; t=1..511: mi=[x[b,t,:],pred]; h=relu(mi@W1+b1); pred=h@W2+b2.
// B=4096,T=512,F=63. R12: 512 WGs x 512 thr (8 waves), 8 batch rows/WG -> 2 WGs/CU
// (two INDEPENDENT recurrence chains interleave per CU; launch_bounds(512,4), lean VGPR).
// All-f16 datapath (R11). Pred feedback re-injected into B-frag k=63 slot (R8-verified
// layout, saves 32 fmaf + 32 VGPR). b1 as MFMA C-init. Layer2 = 4 f16 MFMAs (replicated-row
// W2 frags), 2 parallel chains. Raw lgkm-only barrier; global prefetch stays in flight.

#define TT 512
#define FF 63
#define HID 1024
#define ROWS 8

typedef __attribute__((ext_vector_type(4))) float f32x4;
typedef __attribute__((ext_vector_type(4))) int i32x4;
typedef __attribute__((ext_vector_type(8))) _Float16 h16x8;

// LDS-visibility barrier WITHOUT the vmcnt(0) drain of __syncthreads.
__device__ __forceinline__ void lds_barrier() {
  asm volatile("s_waitcnt lgkmcnt(0)" ::: "memory");
  __builtin_amdgcn_s_barrier();
  asm volatile("" ::: "memory");
}

// pack relu(a),relu(b) -> 2xf16 (RTZ, v_cvt_pkrtz_f16_f32) as int
__device__ __forceinline__ int pkh(float a, float b) {
  auto h = __builtin_amdgcn_cvt_pkrtz(fmaxf(a, 0.f), fmaxf(b, 0.f));
  return __builtin_bit_cast(int, h);
}

__global__ __launch_bounds__(512, 4)
void ffnn_ar_kernel(const float* __restrict__ x,
                    const float* __restrict__ W1,
                    const float* __restrict__ b1,
                    const float* __restrict__ W2,
                    const float* __restrict__ b2p,
                    float* __restrict__ out) {
  __shared__ __align__(16) _Float16 lds_A[2][16][72];  // f16 x-tiles; rows 8..15 zeroed
  __shared__ __align__(16) float lds_part[2][16][12];  // [buf][batch c][wave w]

  const int tid  = threadIdx.x;
  const int lane = tid & 63;
  const int w    = tid >> 6;    // wave 0..7: hidden cols [128w, 128w+128)
  const int c    = lane & 15;   // batch column (C col) / frag row-id
  const int g    = lane >> 4;   // k-group
  const int br   = blockIdx.x * ROWS;

  // ---- one-time weights ----
  // bfr[i][ks]: A1-frag = W1^T (f16): lane (c,g) slot j = W1[ks*32+g*8+j][(w*8+i)*16+c]
  h16x8 bfr[8][2];
#pragma unroll
  for (int i = 0; i < 8; ++i) {
    const int n = (w * 8 + i) * 16 + c;
#pragma unroll
    for (int ks = 0; ks < 2; ++ks) {
      h16x8 f;
#pragma unroll
      for (int j = 0; j < 8; ++j) f[j] = (_Float16)W1[(ks * 32 + g * 8 + j) * HID + n];
      bfr[i][ks] = f;
    }
  }
  // b1v[i]: C-init, lane (c,g) reg q = b1[(w*8+i)*16 + g*4 + q]
  f32x4 b1v[8];
#pragma unroll
  for (int i = 0; i < 8; ++i) {
    const int nb = (w * 8 + i) * 16 + g * 4;
    b1v[i] = (f32x4){b1[nb], b1[nb + 1], b1[nb + 2], b1[nb + 3]};
  }
  // a2f[i2]: f16 A2-frag (rows replicated): slot j = W2[(w*8+2*i2+(j>>2))*16 + g*4 + (j&3)]
  h16x8 a2f[4];
#pragma unroll
  for (int i2 = 0; i2 < 4; ++i2) {
    h16x8 f;
#pragma unroll
    for (int j = 0; j < 8; ++j)
      f[j] = (_Float16)W2[(w * 8 + 2 * i2 + (j >> 2)) * 16 + g * 4 + (j & 3)];
    a2f[i2] = f;
  }
  const float b2 = b2p[0];
  const float b2w = (w == 0) ? b2 : 0.f;  // baked once via wave0's layer-2 C-init

  // ---- x staging: wave w stages batch row w (8 rows); elem = lane (0..62) ----
  const long rowbase = (long)(br + w) * (TT * FF);
  const bool st = (lane < 63);

  // prologue: zero rows 8..15 (both buffers, all 72 cols = 144B -> 36 dwords/row)
  if (tid < 288) {
    const int r  = 8 + tid / 36;
    const int cc = (tid % 36) * 2;
    *reinterpret_cast<unsigned*>(&lds_A[0][r][cc]) = 0u;
    *reinterpret_cast<unsigned*>(&lds_A[1][r][cc]) = 0u;
  }
  // stage x_1 -> buf1; part bufs = 0 (pred_0 = 0); out[:,0] = 0
  if (st) lds_A[1][w][lane] = (_Float16)x[rowbase + FF + lane];
  if (tid < 8) { lds_A[0][tid][63] = (_Float16)0.f; lds_A[1][tid][63] = (_Float16)0.f; }
  if (tid < 384) reinterpret_cast<float*>(lds_part)[tid] = 0.f;
  if (tid < 8) out[(long)(br + tid) * TT] = 0.f;

  // 2 prefetch sets: S0 = x_2, S1 = x_3
  float s0 = st ? x[rowbase + 2 * FF + lane] : 0.f;
  float s1 = st ? x[rowbase + 3 * FF + lane] : 0.f;

  lds_barrier();

#define STEP(T, CUR, S)                                                             \
  {                                                                                 \
    /* gather pred_{T-1}[batch c]: 2x ds_read_b128 + 7-add tree */                  \
    const f32x4 v0 = *reinterpret_cast<const f32x4*>(&lds_part[(CUR) ^ 1][c][0]);   \
    const f32x4 v1 = *reinterpret_cast<const f32x4*>(&lds_part[(CUR) ^ 1][c][4]);   \
    const float pc = ((v0[0] + v0[1]) + (v0[2] + v0[3])) +                          \
                     ((v1[0] + v1[1]) + (v1[2] + v1[3]));                           \
    /* B-frags for x_T; inject pred into k=63 slot (g==3, elem 7) */                \
    const h16x8 xb0 = *reinterpret_cast<const h16x8*>(&lds_A[CUR][c][g * 8]);       \
    h16x8 xb1 = *reinterpret_cast<const h16x8*>(&lds_A[CUR][c][32 + g * 8]);        \
    if (g == 3) xb1[7] = (_Float16)pc;                                              \
    /* layer1: A=W1^T (f16), B=x, C-init=b1 -> z[hidden g*4+q + 16i][batch c] */    \
    f32x4 acc[8];                                                                   \
    _Pragma("unroll") for (int i = 0; i < 8; ++i) {                                 \
      f32x4 z4 = __builtin_amdgcn_mfma_f32_16x16x32_f16(bfr[i][0], xb0, b1v[i], 0, 0, 0); \
      acc[i] = __builtin_amdgcn_mfma_f32_16x16x32_f16(bfr[i][1], xb1, z4, 0, 0, 0); \
    }                                                                               \
    /* store pred_{T-1}: wave0/g0 lanes c<8 own batch row c */                      \
    if (w == 0 && g == 0 && c < ROWS) out[(long)(br + c) * TT + ((T) - 1)] = pc;    \
    /* stage x_{T+1}; prefetch x_{T+3} (stays in flight across raw barrier) */      \
    if (st) lds_A[(CUR) ^ 1][w][lane] = (_Float16)S;                                \
    {                                                                               \
      const int tp = ((T) + 3 < TT) ? (T) + 3 : TT - 1;                             \
      if (st) S = x[rowbase + (long)tp * FF + lane];                                \
    }                                                                               \
    /* h = relu(z) packed f16 (b1 already in acc); layer2 = 4 MFMAs, 2 chains */    \
    f32x4 p2a = {b2w, b2w, b2w, b2w};                                               \
    f32x4 p2b = {0.f, 0.f, 0.f, 0.f};                                               \
    _Pragma("unroll") for (int i2 = 0; i2 < 4; ++i2) {                              \
      const f32x4 u = acc[2 * i2], v = acc[2 * i2 + 1];                             \
      const h16x8 hf = __builtin_bit_cast(h16x8, (i32x4){                           \
          pkh(u[0], u[1]), pkh(u[2], u[3]), pkh(v[0], v[1]), pkh(v[2], v[3])});     \
      if (i2 & 1)                                                                   \
        p2b = __builtin_amdgcn_mfma_f32_16x16x32_f16(a2f[i2], hf, p2b, 0, 0, 0);    \
      else                                                                          \
        p2a = __builtin_amdgcn_mfma_f32_16x16x32_f16(a2f[i2], hf, p2a, 0, 0, 0);    \
    }                                                                               \
    /* wave partial for batch c -> transposed layout [c][w] */                      \
    if (g == 0) lds_part[CUR][c][w] = p2a[0] + p2b[0];                              \
    lds_barrier();                                                                  \
  }

#pragma unroll 1
  for (int t = 1; t + 1 < TT; t += 2) {
    STEP(t, 1, s0)
    STEP(t + 1, 0, s1)
  }
  STEP(TT - 1, 1, s0)  // t = 511 (CUR=1, writes lds_part[1])

  // final: pred_511 from lds_part[1]
  {
    const f32x4 v0 = *reinterpret_cast<const f32x4*>(&lds_part[1][c][0]);
    const f32x4 v1 = *reinterpret_cast<const f32x4*>(&lds_part[1][c][4]);
    const float pc = ((v0[0] + v0[1]) + (v0[2] + v0[3])) +
                     ((v1[0] + v1[1]) + (v1[2] + v1[3]));
    if (w == 0 && g == 0 && c < ROWS) out[(long)(br + c) * TT + (TT - 1)] = pc;
  }
#undef STEP
}

extern "C" void kernel_launch(void* const* d_in, const int* in_sizes, int n_in,
                              void* d_out, int out_size, void* d_ws, size_t ws_size,
                              hipStream_t stream) {
  const float* x   = (const float*)d_in[0];
  // d_in[1] = labels (unused by the reference forward pass)
  const float* W1  = (const float*)d_in[2];
  const float* b1  = (const float*)d_in[3];
  const float* W2  = (const float*)d_in[4];
  const float* b2  = (const float*)d_in[5];
  float* out = (float*)d_out;

  ffnn_ar_kernel<<<512, 512, 0, stream>>>(x, W1, b1, W2, b2, out);
}

// Round 14
// 355.409 us; speedup vs baseline: 8.2541x; 8.2541x over previous
//
#include <hip/hip_runtime.h>

// Autoregressive FFNN. out[b,0]=0; t=1..511: mi=[x[b,t,:],pred]; h=relu(mi@W1+b1); pred=h@W2+b2.
// B=4096,T=512,F=63. 256 WGs x 512 thr (8 waves), 16 rows/WG, persistent, 1 raw barrier/step.
// R13 = R11 (best: all-f16, A=W1^T incl row63, b1 as C-init, VALU pred feedback, transposed
// [c][12] partials, raw lgkm-only barrier) + VALU/DS diet:
//  - packed staging: 1 float2 load + 1 cvt_pkrtz + 1 ds_write_b32 per lane (was 2+2+2);
//    lane31 packs (x[62], 0) which also refreshes col63=0 each step.
//  - gather ds_reads issued first (overlap with 16 independent L1 MFMAs).
//  - layer-2 = 4 independent MFMA chains + 3 scalar adds.

#define TT 512
#define FF 63
#define HID 1024

typedef __attribute__((ext_vector_type(4))) float f32x4;
typedef __attribute__((ext_vector_type(4))) int i32x4;
typedef __attribute__((ext_vector_type(8))) _Float16 h16x8;

struct __attribute__((packed, aligned(4))) uf2 { float x, y; };

// LDS-visibility barrier WITHOUT the vmcnt(0) drain of __syncthreads.
__device__ __forceinline__ void lds_barrier() {
  asm volatile("s_waitcnt lgkmcnt(0)" ::: "memory");
  __builtin_amdgcn_s_barrier();
  asm volatile("" ::: "memory");
}

// pack relu(a),relu(b) -> 2xf16 (RTZ) as int
__device__ __forceinline__ int pkh(float a, float b) {
  auto h = __builtin_amdgcn_cvt_pkrtz(fmaxf(a, 0.f), fmaxf(b, 0.f));
  return __builtin_bit_cast(int, h);
}
// pack a,b -> 2xf16 (RTZ) as int
__device__ __forceinline__ int pk2h(float a, float b) {
  auto h = __builtin_amdgcn_cvt_pkrtz(a, b);
  return __builtin_bit_cast(int, h);
}

__global__ __launch_bounds__(512, 2)
void ffnn_ar_kernel(const float* __restrict__ x,
                    const float* __restrict__ W1,
                    const float* __restrict__ b1,
                    const float* __restrict__ W2,
                    const float* __restrict__ b2p,
                    float* __restrict__ out) {
  __shared__ __align__(16) _Float16 lds_A[2][16][72];  // f16 x-tiles (col63 = 0), 144B rows
  __shared__ __align__(16) float lds_part[2][16][12];  // [buf][batch c][wave w], 48B rows

  const int tid  = threadIdx.x;
  const int lane = tid & 63;
  const int w    = tid >> 6;    // wave 0..7: hidden cols [128w, 128w+128)
  const int c    = lane & 15;   // batch column (C col) / frag row-id
  const int g    = lane >> 4;   // k-group
  const int br   = blockIdx.x * 16;

  // ---- one-time weights ----
  // bfr[i][ks]: A1-frag = W1^T (f16): lane (c,g) slot j = W1[ks*32+g*8+j][(w*8+i)*16+c]
  // (includes k=63 = W1[63][n]; LDS col63 = 0 so its MFMA term is 0; feedback via VALU)
  h16x8 bfr[8][2];
#pragma unroll
  for (int i = 0; i < 8; ++i) {
    const int n = (w * 8 + i) * 16 + c;
#pragma unroll
    for (int ks = 0; ks < 2; ++ks) {
      h16x8 f;
#pragma unroll
      for (int j = 0; j < 8; ++j) f[j] = (_Float16)W1[(ks * 32 + g * 8 + j) * HID + n];
      bfr[i][ks] = f;
    }
  }
  // b1v[i]: C-init, lane (c,g) reg q = b1[(w*8+i)*16 + g*4 + q]; w63v: feedback weights
  f32x4 b1v[8], w63v[8];
#pragma unroll
  for (int i = 0; i < 8; ++i) {
    const int nb = (w * 8 + i) * 16 + g * 4;
    b1v[i]  = (f32x4){b1[nb], b1[nb + 1], b1[nb + 2], b1[nb + 3]};
    w63v[i] = (f32x4){W1[63 * HID + nb], W1[63 * HID + nb + 1],
                      W1[63 * HID + nb + 2], W1[63 * HID + nb + 3]};
  }
  // a2f[i2]: f16 A2-frag (rows replicated): slot j = W2[(w*8+2*i2+(j>>2))*16 + g*4 + (j&3)]
  h16x8 a2f[4];
#pragma unroll
  for (int i2 = 0; i2 < 4; ++i2) {
    h16x8 f;
#pragma unroll
    for (int j = 0; j < 8; ++j)
      f[j] = (_Float16)W2[(w * 8 + 2 * i2 + (j >> 2)) * 16 + g * 4 + (j & 3)];
    a2f[i2] = f;
  }
  const float b2 = b2p[0];
  const float b2w = (w == 0) ? b2 : 0.f;  // baked once via wave0's layer-2 chain-a C-init

  // ---- x staging: 16 groups of 32 threads, one row each; packed 2 elems/lane ----
  const int srow = tid >> 5;   // 0..15
  const int sl   = tid & 31;   // 0..31 (lane 31: elem 62 + zero -> also clears col63)
  const long rowbase = (long)(br + srow) * (TT * FF);
  const bool full = (sl < 31);

  // prologue: stage x_1 -> buf1 (packed); part bufs = 0; out[:,0] = 0
  {
    float xa, xb;
    if (full) { const uf2 v = *reinterpret_cast<const uf2*>(&x[rowbase + FF + 2 * sl]); xa = v.x; xb = v.y; }
    else      { xa = x[rowbase + FF + 62]; xb = 0.f; }
    *reinterpret_cast<int*>(&lds_A[1][srow][2 * sl]) = pk2h(xa, xb);
  }
  if (tid < 384) reinterpret_cast<float*>(lds_part)[tid] = 0.f;  // both bufs -> pred_0 = 0
  if (tid < 16) out[(long)(br + tid) * TT] = 0.f;                // out[:,0] = 0

  // 2 prefetch sets: S0 = x_2, S1 = x_3
  float s0a, s0b, s1a, s1b;
  if (full) {
    const uf2 v0 = *reinterpret_cast<const uf2*>(&x[rowbase + 2 * FF + 2 * sl]);
    const uf2 v1 = *reinterpret_cast<const uf2*>(&x[rowbase + 3 * FF + 2 * sl]);
    s0a = v0.x; s0b = v0.y; s1a = v1.x; s1b = v1.y;
  } else {
    s0a = x[rowbase + 2 * FF + 62]; s0b = 0.f;
    s1a = x[rowbase + 3 * FF + 62]; s1b = 0.f;
  }

  lds_barrier();

#define STEP(T, CUR, SA, SB)                                                        \
  {                                                                                 \
    /* gather pred_{T-1}[batch c] FIRST: 2x ds_read_b128 (overlaps L1 MFMAs) */     \
    const f32x4 v0 = *reinterpret_cast<const f32x4*>(&lds_part[(CUR) ^ 1][c][0]);   \
    const f32x4 v1 = *reinterpret_cast<const f32x4*>(&lds_part[(CUR) ^ 1][c][4]);   \
    /* x frags (f16) — no pred dependency: MFMAs issue immediately */               \
    const h16x8 xb0 = *reinterpret_cast<const h16x8*>(&lds_A[CUR][c][g * 8]);       \
    const h16x8 xb1 = *reinterpret_cast<const h16x8*>(&lds_A[CUR][c][32 + g * 8]);  \
    f32x4 acc[8];                                                                   \
    _Pragma("unroll") for (int i = 0; i < 8; ++i) {                                 \
      f32x4 z4 = __builtin_amdgcn_mfma_f32_16x16x32_f16(bfr[i][0], xb0, b1v[i], 0, 0, 0); \
      acc[i] = __builtin_amdgcn_mfma_f32_16x16x32_f16(bfr[i][1], xb1, z4, 0, 0, 0); \
    }                                                                               \
    const float pc = ((v0[0] + v0[1]) + (v0[2] + v0[3])) +                          \
                     ((v1[0] + v1[1]) + (v1[2] + v1[3]));                           \
    if (w == 0 && g == 0) out[(long)(br + c) * TT + ((T) - 1)] = pc;                \
    /* stage x_{T+1} (packed); prefetch x_{T+3} (stays in flight across barrier) */ \
    *reinterpret_cast<int*>(&lds_A[(CUR) ^ 1][srow][2 * sl]) = pk2h(SA, SB);        \
    {                                                                               \
      const int tp = ((T) + 3 < TT) ? (T) + 3 : TT - 1;                             \
      if (full) { const uf2 v = *reinterpret_cast<const uf2*>(&x[rowbase + (long)tp * FF + 2 * sl]); \
                  SA = v.x; SB = v.y; }                                             \
      else      { SA = x[rowbase + (long)tp * FF + 62]; }                           \
    }                                                                               \
    /* epilogue: z += pc*W1[63]; h=relu packed f16; layer2 = 4 independent chains */\
    f32x4 p2a = {b2w, b2w, b2w, b2w};                                               \
    f32x4 p2b = {0.f, 0.f, 0.f, 0.f};                                               \
    f32x4 p2c = {0.f, 0.f, 0.f, 0.f};                                               \
    f32x4 p2d = {0.f, 0.f, 0.f, 0.f};                                               \
    _Pragma("unroll") for (int i2 = 0; i2 < 4; ++i2) {                              \
      const f32x4 u = acc[2 * i2], v = acc[2 * i2 + 1];                             \
      const f32x4 wu = w63v[2 * i2], wv = w63v[2 * i2 + 1];                         \
      const h16x8 hf = __builtin_bit_cast(h16x8, (i32x4){                           \
          pkh(fmaf(pc, wu[0], u[0]), fmaf(pc, wu[1], u[1])),                        \
          pkh(fmaf(pc, wu[2], u[2]), fmaf(pc, wu[3], u[3])),                        \
          pkh(fmaf(pc, wv[0], v[0]), fmaf(pc, wv[1], v[1])),                        \
          pkh(fmaf(pc, wv[2], v[2]), fmaf(pc, wv[3], v[3]))});                      \
      if (i2 == 0)      p2a = __builtin_amdgcn_mfma_f32_16x16x32_f16(a2f[0], hf, p2a, 0, 0, 0); \
      else if (i2 == 1) p2b = __builtin_amdgcn_mfma_f32_16x16x32_f16(a2f[1], hf, p2b, 0, 0, 0); \
      else if (i2 == 2) p2c = __builtin_amdgcn_mfma_f32_16x16x32_f16(a2f[2], hf, p2c, 0, 0, 0); \
      else              p2d = __builtin_amdgcn_mfma_f32_16x16x32_f16(a2f[3], hf, p2d, 0, 0, 0); \
    }                                                                               \
    if (g == 0) lds_part[CUR][c][w] = (p2a[0] + p2b[0]) + (p2c[0] + p2d[0]);        \
    lds_barrier();                                                                  \
  }

#pragma unroll 1
  for (int t = 1; t + 1 < TT; t += 2) {
    STEP(t, 1, s0a, s0b)
    STEP(t + 1, 0, s1a, s1b)
  }
  STEP(TT - 1, 1, s0a, s0b)  // t = 511 (CUR=1, writes lds_part[1])

  // final: pred_511 from lds_part[1]
  {
    const f32x4 v0 = *reinterpret_cast<const f32x4*>(&lds_part[1][c][0]);
    const f32x4 v1 = *reinterpret_cast<const f32x4*>(&lds_part[1][c][4]);
    const float pc = ((v0[0] + v0[1]) + (v0[2] + v0[3])) +
                     ((v1[0] + v1[1]) + (v1[2] + v1[3]));
    if (w == 0 && g == 0) out[(long)(br + c) * TT + (TT - 1)] = pc;
  }
#undef STEP
}

extern "C" void kernel_launch(void* const* d_in, const int* in_sizes, int n_in,
                              void* d_out, int out_size, void* d_ws, size_t ws_size,
                              hipStream_t stream) {
  const float* x   = (const float*)d_in[0];
  // d_in[1] = labels (unused by the reference forward pass)
  const float* W1  = (const float*)d_in[2];
  const float* b1  = (const float*)d_in[3];
  const float* W2  = (const float*)d_in[4];
  const float* b2  = (const float*)d_in[5];
  float* out = (float*)d_out;

  ffnn_ar_kernel<<<256, 512, 0, stream>>>(x, W1, b1, W2, b2, out);
}